// Round 9
// baseline (180.214 us; speedup 1.0000x reference)
//
#include <hip/hip_runtime.h>
#include <hip/hip_fp16.h>

#define LOG2PI_F 1.8378770664093453f

// Fixed problem sizes (reference: N_TFH=1000, N_TG=20000).
// ws table layout: [0, N_TG) = TG entries, [N_TG, N_TG+N_TFH) = TF_high.
#define N_TG_C   20000
#define N_TFH_C  1000
#define N_TOT_C  (N_TG_C + N_TFH_C)          // 21000 entries
#define TG_BYTES (N_TG_C * 4)                // 80000 B (fits 2 blocks/CU)

// ext_vector types: __builtin_nontemporal_load requires scalar/vector types.
typedef float f32x4 __attribute__((ext_vector_type(4)));
typedef int   i32x4 __attribute__((ext_vector_type(4)));

// Pack (mu, sigma) as two fp16 in one u32 (absmax 0.0 in rounds 1/8).
static __device__ __forceinline__ uint32_t pack_musig(float mu, float sig) {
    __half2 h = __floats2half2_rn(mu, sig);
    return *reinterpret_cast<const uint32_t*>(&h);
}
static __device__ __forceinline__ float2 unpack_musig(uint32_t v) {
    __half2 h = *reinterpret_cast<const __half2*>(&v);
    return __half22float2(h);   // .x = mu, .y = sigma
}

// ---------------------------------------------------------------------------
// Prologue (proven): build packed combined table in ws, fold p/q terms + the
// per-edge 0.5*log2pi constant into out.  ws: [tbl: u32 x 21000].
// (ws is re-poisoned by the harness every launch — must run each time; reads
// only 336 KB.)
// ---------------------------------------------------------------------------
__global__ __launch_bounds__(256) void pack_kernel(
    const float* __restrict__ TF_high_mu,
    const float* __restrict__ TF_high_sigma,
    const float* __restrict__ TG_mu,
    const float* __restrict__ TG_sigma,
    const float* __restrict__ TF_high_exp,
    const float* __restrict__ TG_exp,
    const int*  __restrict__ father_num,
    uint32_t* __restrict__ ws_tbl,
    float* __restrict__ out,
    int n_tfh, int n_tg, int n_e)
{
    const int tid = blockIdx.x * blockDim.x + threadIdx.x;
    const int nth = gridDim.x * blockDim.x;

    float acc = 0.0f;

    for (int i = tid; i < n_tg; i += nth) {
        float mu = TG_mu[i], sig = TG_sigma[i];
        ws_tbl[i] = pack_musig(mu, sig);
        // q term (full fp32 precision)
        float z = (TG_exp[i] - mu) / sig;
        float lp = -0.5f * z * z - __logf(sig) - 0.5f * LOG2PI_F;
        acc += ((float)father_num[i] - 1.0f) * lp;   // contributes -q
    }

    for (int i = tid; i < n_tfh; i += nth) {
        float mu = TF_high_mu[i], sig = TF_high_sigma[i];
        ws_tbl[N_TG_C + i] = pack_musig(mu, sig);
        // p term
        float z = (TF_high_exp[i] - mu) / sig;
        float lp = -0.5f * z * z - __logf(sig) - 0.5f * LOG2PI_F;
        acc -= lp;                                   // contributes -p
    }

    // each edge contributes +0.5*log2pi to the final negated sum; fold once
    if (tid == 0) acc += 0.5f * LOG2PI_F * (float)n_e;

    #pragma unroll
    for (int off = 32; off > 0; off >>= 1)
        acc += __shfl_down(acc, off, 64);

    __shared__ float wave_sums[4];
    const int lane = threadIdx.x & 63;
    const int wave = threadIdx.x >> 6;
    if (lane == 0) wave_sums[wave] = acc;
    __syncthreads();
    if (threadIdx.x == 0) {
        float s = wave_sums[0] + wave_sums[1] + wave_sums[2] + wave_sums[3];
        atomicAdd(out, s);
    }
}

// ---------------------------------------------------------------------------
// Main: edge term — the JOINT cell {2 DS/edge AND 32 waves/CU}.
//  - LDS holds ONLY the TG table: 80000 B -> 2 blocks/CU x 1024 thr =
//    32 waves/CU (R7 had 32 waves but 4 DS; R8 had 2 DS but 16 waves).
//  - TF_high table (1000 u32 = 4 KB) stays in global: L1-resident, one
//    cached gather per edge, selected branchlessly against the LDS read.
//  - NT loads for the 9 once-read streams (round-7 proven L3-bypass).
//  - fp16 table numerics (absmax 0.0 in round 8).
//  - __launch_bounds__(1024, 8): VGPR cap 64 (lean R4-style body fit in 28).
// ---------------------------------------------------------------------------
__global__ __launch_bounds__(1024, 8) void edge_kernel(
    const uint32_t* __restrict__ ws_tbl,
    const float* __restrict__ k_edge,
    const float* __restrict__ alpha,
    const float* __restrict__ cov,
    const float* __restrict__ edge_y,
    const float* __restrict__ edge_x,
    const int*  __restrict__ idx_tf_tg,
    const int*  __restrict__ idx_tf_high,
    const int*  __restrict__ edge_tg_idx,
    const int*  __restrict__ is_high,
    float* __restrict__ out,
    int n_e)
{
    __shared__ uint32_t s_tg[N_TG_C];          // 80000 B  (TG entries only)
    __shared__ float wave_sums[16];            // 1024 threads = 16 waves

    // cooperative fill (coalesced u32 copy; source is L2-hot across blocks)
    for (int w = threadIdx.x; w < N_TG_C; w += 1024) s_tg[w] = ws_tbl[w];
    __syncthreads();

    const uint32_t* __restrict__ g_hi = ws_tbl + N_TG_C;   // 4 KB, L1-hot

    const int tid = blockIdx.x * blockDim.x + threadIdx.x;
    const int nth = gridDim.x * blockDim.x;

    float acc = 0.0f;   // accumulates -(lp + 0.5*log2pi) per edge

    const int nvec = n_e >> 2;
    const f32x4* k4 = (const f32x4*)k_edge;
    const f32x4* a4 = (const f32x4*)alpha;
    const f32x4* c4 = (const f32x4*)cov;
    const f32x4* y4 = (const f32x4*)edge_y;
    const f32x4* x4 = (const f32x4*)edge_x;
    const i32x4* ih4 = (const i32x4*)is_high;
    const i32x4* iH4 = (const i32x4*)idx_tf_high;
    const i32x4* iT4 = (const i32x4*)idx_tf_tg;
    const i32x4* iG4 = (const i32x4*)edge_tg_idx;

    for (int i = tid; i < nvec; i += nth) {
        // nontemporal: 144 MB read exactly once — bypass L2/L3 fill
        i32x4 ih = __builtin_nontemporal_load(ih4 + i);
        i32x4 iH = __builtin_nontemporal_load(iH4 + i);
        i32x4 iT = __builtin_nontemporal_load(iT4 + i);
        i32x4 iG = __builtin_nontemporal_load(iG4 + i);

        // tf candidate from the 4 KB L1-hot global table (cached load)
        uint32_t pg0 = g_hi[iH[0]], pg1 = g_hi[iH[1]];
        uint32_t pg2 = g_hi[iH[2]], pg3 = g_hi[iH[3]];
        // tf candidate + tg from LDS (2 DS ops per edge)
        uint32_t pl0 = s_tg[iT[0]], pl1 = s_tg[iT[1]];
        uint32_t pl2 = s_tg[iT[2]], pl3 = s_tg[iT[3]];
        uint32_t ptg0 = s_tg[iG[0]], ptg1 = s_tg[iG[1]];
        uint32_t ptg2 = s_tg[iG[2]], ptg3 = s_tg[iG[3]];

        // branchless select
        uint32_t ptf0 = ih[0] ? pg0 : pl0;
        uint32_t ptf1 = ih[1] ? pg1 : pl1;
        uint32_t ptf2 = ih[2] ? pg2 : pl2;
        uint32_t ptf3 = ih[3] ? pg3 : pl3;

        f32x4 k = __builtin_nontemporal_load(k4 + i);
        f32x4 a = __builtin_nontemporal_load(a4 + i);
        f32x4 c = __builtin_nontemporal_load(c4 + i);
        f32x4 y = __builtin_nontemporal_load(y4 + i);
        f32x4 x = __builtin_nontemporal_load(x4 + i);

        {
            float2 tf = unpack_musig(ptf0); float2 tg = unpack_musig(ptg0);
            float ivar = 1.0f / (tf.y * tf.y);
            float loc  = fmaxf(fmaf(k[0] * c[0], (y[0] - tf.x) * ivar, tg.x), 0.0f) + 0.01f;
            float v    = fmaxf(fmaf(-a[0] * a[0], ivar, tg.y * tg.y), 0.0f) + 0.01f;
            float d    = x[0] - loc;
            acc += 0.5f * (d * d / v + __logf(v));
        }
        {
            float2 tf = unpack_musig(ptf1); float2 tg = unpack_musig(ptg1);
            float ivar = 1.0f / (tf.y * tf.y);
            float loc  = fmaxf(fmaf(k[1] * c[1], (y[1] - tf.x) * ivar, tg.x), 0.0f) + 0.01f;
            float v    = fmaxf(fmaf(-a[1] * a[1], ivar, tg.y * tg.y), 0.0f) + 0.01f;
            float d    = x[1] - loc;
            acc += 0.5f * (d * d / v + __logf(v));
        }
        {
            float2 tf = unpack_musig(ptf2); float2 tg = unpack_musig(ptg2);
            float ivar = 1.0f / (tf.y * tf.y);
            float loc  = fmaxf(fmaf(k[2] * c[2], (y[2] - tf.x) * ivar, tg.x), 0.0f) + 0.01f;
            float v    = fmaxf(fmaf(-a[2] * a[2], ivar, tg.y * tg.y), 0.0f) + 0.01f;
            float d    = x[2] - loc;
            acc += 0.5f * (d * d / v + __logf(v));
        }
        {
            float2 tf = unpack_musig(ptf3); float2 tg = unpack_musig(ptg3);
            float ivar = 1.0f / (tf.y * tf.y);
            float loc  = fmaxf(fmaf(k[3] * c[3], (y[3] - tf.x) * ivar, tg.x), 0.0f) + 0.01f;
            float v    = fmaxf(fmaf(-a[3] * a[3], ivar, tg.y * tg.y), 0.0f) + 0.01f;
            float d    = x[3] - loc;
            acc += 0.5f * (d * d / v + __logf(v));
        }
    }

    // tail (n_e not divisible by 4) — plain loads, tiny
    for (int j = (nvec << 2) + tid; j < n_e; j += nth) {
        uint32_t ptf = is_high[j] ? g_hi[idx_tf_high[j]] : s_tg[idx_tf_tg[j]];
        float2 tf = unpack_musig(ptf);
        float2 tg = unpack_musig(s_tg[edge_tg_idx[j]]);
        float ivar = 1.0f / (tf.y * tf.y);
        float loc  = fmaxf(fmaf(k_edge[j] * cov[j], (edge_y[j] - tf.x) * ivar, tg.x), 0.0f) + 0.01f;
        float v    = fmaxf(fmaf(-alpha[j] * alpha[j], ivar, tg.y * tg.y), 0.0f) + 0.01f;
        float d    = edge_x[j] - loc;
        acc += 0.5f * (d * d / v + __logf(v));
    }

    // ---- reduction ----
    #pragma unroll
    for (int off = 32; off > 0; off >>= 1)
        acc += __shfl_down(acc, off, 64);

    const int lane = threadIdx.x & 63;
    const int wave = threadIdx.x >> 6;
    if (lane == 0) wave_sums[wave] = acc;
    __syncthreads();
    if (threadIdx.x == 0) {
        float s = 0.0f;
        #pragma unroll
        for (int w = 0; w < 16; ++w) s += wave_sums[w];
        atomicAdd(out, s);
    }
}

extern "C" void kernel_launch(void* const* d_in, const int* in_sizes, int n_in,
                              void* d_out, int out_size, void* d_ws, size_t ws_size,
                              hipStream_t stream)
{
    const float* TF_high_mu    = (const float*)d_in[0];
    const float* TF_high_sigma = (const float*)d_in[1];
    const float* TG_mu         = (const float*)d_in[2];
    const float* TG_sigma      = (const float*)d_in[3];
    const float* TF_high_exp   = (const float*)d_in[4];
    const float* TG_exp        = (const float*)d_in[5];
    const float* k_edge        = (const float*)d_in[6];
    const float* alpha         = (const float*)d_in[7];
    const float* cov           = (const float*)d_in[8];
    const float* edge_y        = (const float*)d_in[9];
    const float* edge_x        = (const float*)d_in[10];
    const int*  father_num     = (const int*)d_in[11];
    const int*  idx_tf_tg      = (const int*)d_in[12];
    const int*  idx_tf_high    = (const int*)d_in[13];
    const int*  edge_tg_idx    = (const int*)d_in[14];
    const int*  is_high        = (const int*)d_in[15];

    const int n_tfh = in_sizes[0];
    const int n_tg  = in_sizes[2];
    const int n_e   = in_sizes[6];

    // ws layout: [tbl: u32 x 21000] (fp16 mu | fp16 sig); TG first, TF_high
    // at +N_TG (the global 4 KB tail the edge kernel gathers from directly)
    uint32_t* ws_tbl = (uint32_t*)d_ws;

    // d_out poisoned 0xAA each launch — zero it (capture-safe)
    hipMemsetAsync(d_out, 0, sizeof(float), stream);

    hipLaunchKernelGGL(pack_kernel, dim3(84), dim3(256), 0, stream,
                       TF_high_mu, TF_high_sigma, TG_mu, TG_sigma,
                       TF_high_exp, TG_exp, father_num,
                       ws_tbl, (float*)d_out, n_tfh, n_tg, n_e);

    // 512 blocks x 1024 threads: 2 blocks/CU (80 KB LDS each), 32 waves/CU;
    // 2 DS + 1 L1-gather per edge; ~1.9 float4-groups per thread.
    hipLaunchKernelGGL(edge_kernel, dim3(512), dim3(1024), 0, stream,
                       ws_tbl, k_edge, alpha, cov, edge_y, edge_x,
                       idx_tf_tg, idx_tf_high, edge_tg_idx, is_high,
                       (float*)d_out, n_e);
}